// Round 1
// baseline (240.649 us; speedup 1.0000x reference)
//
#include <hip/hip_runtime.h>
#include <stdint.h>

typedef int v4i __attribute__((ext_vector_type(4)));

#define K_DIM 4096
#define TPB_Q 256
#define BM 128
#define BN 128
#define BK 64

__device__ __forceinline__ void load_lds16(const void* g, void* l) {
  __builtin_amdgcn_global_load_lds(
      (const __attribute__((address_space(1))) void*)g,
      (__attribute__((address_space(3))) void*)l,
      16, 0, 0);
}

// One block per row: compute max|row|, scale, quantize to int8 (packed), store scale.
__global__ __launch_bounds__(TPB_Q) void quant_rows_kernel(
    const float* __restrict__ x, signed char* __restrict__ q,
    float* __restrict__ scales) {
  const int row = blockIdx.x;
  const float4* xr = (const float4*)(x + (size_t)row * K_DIM);
  float4 v[4];
  float m = 0.0f;
#pragma unroll
  for (int i = 0; i < 4; ++i) {
    v[i] = xr[threadIdx.x + i * TPB_Q];
    m = fmaxf(m, fmaxf(fmaxf(fabsf(v[i].x), fabsf(v[i].y)),
                       fmaxf(fabsf(v[i].z), fabsf(v[i].w))));
  }
#pragma unroll
  for (int off = 32; off > 0; off >>= 1) m = fmaxf(m, __shfl_down(m, off));
  __shared__ float red[TPB_Q / 64];
  if ((threadIdx.x & 63) == 0) red[threadIdx.x >> 6] = m;
  __syncthreads();
  m = fmaxf(fmaxf(red[0], red[1]), fmaxf(red[2], red[3]));
  const float scale = fmaxf(m / 127.0f, 1e-8f);  // match reference exactly (IEEE div)
  if (threadIdx.x == 0) scales[row] = scale;
  uint32_t* qr = (uint32_t*)(q + (size_t)row * K_DIM);
#pragma unroll
  for (int i = 0; i < 4; ++i) {
    const float4 t = v[i];
    const int a0 = (int)fminf(fmaxf(rintf(t.x / scale), -128.0f), 127.0f);
    const int a1 = (int)fminf(fmaxf(rintf(t.y / scale), -128.0f), 127.0f);
    const int a2 = (int)fminf(fmaxf(rintf(t.z / scale), -128.0f), 127.0f);
    const int a3 = (int)fminf(fmaxf(rintf(t.w / scale), -128.0f), 127.0f);
    const uint32_t p = (uint32_t)(a0 & 255) | ((uint32_t)(a1 & 255) << 8) |
                       ((uint32_t)(a2 & 255) << 16) | ((uint32_t)(a3 & 255) << 24);
    qr[threadIdx.x + i * TPB_Q] = p;
  }
}

// int8 GEMM, C[m][n] = sum_k qA[m][k]*qB[n][k], dequant epilogue.
// 128x128 tile, BK=64, 4 waves each owning a 64x64 quadrant (4x4 16x16x64 frags).
__global__ __launch_bounds__(256) void gemm_i8_kernel(
    const signed char* __restrict__ qA, const signed char* __restrict__ qB,
    const float* __restrict__ sA, const float* __restrict__ sB,
    float* __restrict__ C, int M, int N, int K) {
  __shared__ __align__(16) signed char As[BM * BK];  // 8 KiB
  __shared__ __align__(16) signed char Bs[BN * BK];  // 8 KiB
  const int tid = threadIdx.x;
  const int wave = tid >> 6;
  const int lane = tid & 63;
  const int l16 = lane & 15;
  const int lhi = lane >> 4;
  const int wr = wave >> 1;  // wave row quadrant (0..1)
  const int wc = wave & 1;   // wave col quadrant (0..1)
  const int m0 = blockIdx.y * BM;
  const int n0 = blockIdx.x * BN;

  const signed char* Ab = qA + (size_t)m0 * K;
  const signed char* Bb = qB + (size_t)n0 * K;

  const v4i vzero = {0, 0, 0, 0};
  v4i acc[4][4];
#pragma unroll
  for (int i = 0; i < 4; ++i)
#pragma unroll
    for (int j = 0; j < 4; ++j) acc[i][j] = vzero;

  for (int kt = 0; kt < K; kt += BK) {
    // stage A tile: 128 rows x 64 B = 8192 B = 2 calls x (256 thr x 16 B)
#pragma unroll
    for (int s = 0; s < 2; ++s) {
      const int c = s * 256 + tid;           // chunk id, 16 B each
      const int row = c >> 2;
      const int ko = (c & 3) << 4;
      load_lds16(Ab + (size_t)row * K + kt + ko,
                 As + (s * 256 + wave * 64) * 16);  // wave-uniform LDS base
    }
#pragma unroll
    for (int s = 0; s < 2; ++s) {
      const int c = s * 256 + tid;
      const int row = c >> 2;
      const int ko = (c & 3) << 4;
      load_lds16(Bb + (size_t)row * K + kt + ko,
                 Bs + (s * 256 + wave * 64) * 16);
    }
    __syncthreads();  // compiler drains vmcnt before s_barrier -> LDS valid

    v4i a[4], b[4];
#pragma unroll
    for (int i = 0; i < 4; ++i)
      a[i] = *(const v4i*)(As + ((wr * 64 + i * 16 + l16) * 64 + lhi * 16));
#pragma unroll
    for (int j = 0; j < 4; ++j)
      b[j] = *(const v4i*)(Bs + ((wc * 64 + j * 16 + l16) * 64 + lhi * 16));
#pragma unroll
    for (int i = 0; i < 4; ++i)
#pragma unroll
      for (int j = 0; j < 4; ++j)
        acc[i][j] = __builtin_amdgcn_mfma_i32_16x16x64_i8(a[i], b[j], acc[i][j], 0, 0, 0);
    __syncthreads();  // protect LDS before next stage overwrites
  }

  // epilogue: C/D layout col = lane&15, row = (lane>>4)*4 + reg  (dtype-independent)
  float sbv[4];
#pragma unroll
  for (int j = 0; j < 4; ++j) sbv[j] = sB[n0 + wc * 64 + j * 16 + l16];
#pragma unroll
  for (int i = 0; i < 4; ++i) {
#pragma unroll
    for (int r = 0; r < 4; ++r) {
      const int row = m0 + wr * 64 + i * 16 + lhi * 4 + r;
      const float sav = sA[row];
      float* crow = C + (size_t)row * N + (n0 + wc * 64 + l16);
#pragma unroll
      for (int j = 0; j < 4; ++j)
        crow[j * 16] = (float)acc[i][j][r] * sav * sbv[j];
    }
  }
}

extern "C" void kernel_launch(void* const* d_in, const int* in_sizes, int n_in,
                              void* d_out, int out_size, void* d_ws, size_t ws_size,
                              hipStream_t stream) {
  const float* A = (const float*)d_in[0];
  const float* B = (const float*)d_in[1];
  float* C = (float*)d_out;
  const int K = K_DIM;
  const int M = in_sizes[0] / K;  // 8192
  const int N = in_sizes[1] / K;  // 4096

  signed char* qA = (signed char*)d_ws;
  signed char* qB = qA + (size_t)M * K;
  float* sA = (float*)(qB + (size_t)N * K);
  float* sB = sA + M;

  quant_rows_kernel<<<M, TPB_Q, 0, stream>>>(A, qA, sA);
  quant_rows_kernel<<<N, TPB_Q, 0, stream>>>(B, qB, sB);

  dim3 grid(N / BN, M / BM);
  gemm_i8_kernel<<<grid, 256, 0, stream>>>(qA, qB, sA, sB, C, M, N, K);
}

// Round 4
// 200.703 us; speedup vs baseline: 1.1990x; 1.1990x over previous
//
#include <hip/hip_runtime.h>
#include <stdint.h>

typedef int v4i __attribute__((ext_vector_type(4)));

#define K_DIM 4096
#define TPB_Q 256
#define BM 256
#define BN 256
#define BKB 128                     // K-bytes (= i8 elements) per tile
#define NT (K_DIM / BKB)            // 32 K-tiles
#define HALF_BYTES (128 * BKB)      // one half-tile: 128 rows x 128 B = 16 KiB

__device__ __forceinline__ void load_lds16(const void* g, void* l) {
  __builtin_amdgcn_global_load_lds(
      (const __attribute__((address_space(1))) void*)g,
      (__attribute__((address_space(3))) void*)l, 16, 0, 0);
}

// ---------------- per-row symmetric int8 quant (BW-bound, unchanged) --------
__global__ __launch_bounds__(TPB_Q) void quant_rows_kernel(
    const float* __restrict__ x, signed char* __restrict__ q,
    float* __restrict__ scales) {
  const int row = blockIdx.x;
  const float4* xr = (const float4*)(x + (size_t)row * K_DIM);
  float4 v[4];
  float m = 0.0f;
#pragma unroll
  for (int i = 0; i < 4; ++i) {
    v[i] = xr[threadIdx.x + i * TPB_Q];
    m = fmaxf(m, fmaxf(fmaxf(fabsf(v[i].x), fabsf(v[i].y)),
                       fmaxf(fabsf(v[i].z), fabsf(v[i].w))));
  }
#pragma unroll
  for (int off = 32; off > 0; off >>= 1) m = fmaxf(m, __shfl_down(m, off));
  __shared__ float red[TPB_Q / 64];
  if ((threadIdx.x & 63) == 0) red[threadIdx.x >> 6] = m;
  __syncthreads();
  m = fmaxf(fmaxf(red[0], red[1]), fmaxf(red[2], red[3]));
  const float scale = fmaxf(m / 127.0f, 1e-8f);
  if (threadIdx.x == 0) scales[row] = scale;
  uint32_t* qr = (uint32_t*)(q + (size_t)row * K_DIM);
#pragma unroll
  for (int i = 0; i < 4; ++i) {
    const float4 t = v[i];
    const int a0 = (int)fminf(fmaxf(rintf(t.x / scale), -128.0f), 127.0f);
    const int a1 = (int)fminf(fmaxf(rintf(t.y / scale), -128.0f), 127.0f);
    const int a2 = (int)fminf(fmaxf(rintf(t.z / scale), -128.0f), 127.0f);
    const int a3 = (int)fminf(fmaxf(rintf(t.w / scale), -128.0f), 127.0f);
    const uint32_t p = (uint32_t)(a0 & 255) | ((uint32_t)(a1 & 255) << 8) |
                       ((uint32_t)(a2 & 255) << 16) | ((uint32_t)(a3 & 255) << 24);
    qr[threadIdx.x + i * TPB_Q] = p;
  }
}

// ---------------- 256x256 8-phase i8 GEMM --------------------------------
// 8 waves: wm=wave>>2 (2), wn=wave&3 (4). Per-wave C: 128x64 = acc[8][4].
// LDS: per operand 2 dbuf x 2 halves x (128 rows x 128 B), XOR-swizzled
// at 16B-chunk granularity: phys_chunk = logical_chunk ^ (row & 7).
// Schedule per K-tile T (4 phases):
//   P1: read all B frags + a[0..1]; stage A1(T+1); bar; lgkm0; MFMA mi0-1; bar
//   P2: read a[2..4];               stage B0(T+2); bar; lgkm0; MFMA mi2-3; bar
//   P3: read a[5..7];               stage B1(T+2); bar; lgkm0; MFMA mi4-5; bar
//   P4: (no reads)                  stage A0(T+2); bar; MFMA mi6-7; vmcnt(6); bar
// Safety: B regions of buf[T&1] are fully read in P1 (stage @P2/P3 is >=1
// phase later); A regions fully read by P3 (stage @P4 later). Availability:
// vmcnt(6) leaves only the 3 most-recent half-tile stages (= tile T+2's)
// outstanding; tile T+1 (staged @ G-1.P2..P4 + G.P1) is landed.
__global__ __launch_bounds__(512, 2) void gemm_i8_kernel(
    const signed char* __restrict__ qA, const signed char* __restrict__ qB,
    const float* __restrict__ sA, const float* __restrict__ sB,
    float* __restrict__ C, int M, int N, int K) {
  __shared__ __align__(16) signed char As[4 * HALF_BYTES];  // 64 KiB
  __shared__ __align__(16) signed char Bs[4 * HALF_BYTES];  // 64 KiB

  const int tid = threadIdx.x;
  const int wave = tid >> 6, lane = tid & 63;
  const int l16 = lane & 15, lhi = lane >> 4;
  const int wm = wave >> 2, wn = wave & 3;
  const int m0 = blockIdx.y * BM, n0 = blockIdx.x * BN;

  const signed char* Abase = qA + (size_t)m0 * K;
  const signed char* Bbase = qB + (size_t)n0 * K;

  // staging: half-tile = 1024 x 16B chunks; thread handles chunks d = s*512+tid.
  // dest is linear (wave-uniform base + lane*16); source is inverse-swizzled.
  int soff[2], sdst[2];
#pragma unroll
  for (int s = 0; s < 2; ++s) {
    const int d = s * 512 + tid;
    const int r = d >> 3;                 // row within half
    const int c = (d & 7) ^ (r & 7);      // logical chunk held at phys (d&7)
    soff[s] = r * K + c * 16;
    sdst[s] = s * 8192 + wave * 1024;
  }

#define STAGE_A(T_, h_)                                                     \
  do {                                                                      \
    _Pragma("unroll") for (int s = 0; s < 2; ++s)                           \
        load_lds16(Abase + (size_t)(h_)*128 * K + (T_)*BKB + soff[s],       \
                   As + (((T_)&1) * 2 + (h_)) * HALF_BYTES + sdst[s]);      \
  } while (0)
#define STAGE_B(T_, h_)                                                     \
  do {                                                                      \
    _Pragma("unroll") for (int s = 0; s < 2; ++s)                           \
        load_lds16(Bbase + (size_t)(h_)*128 * K + (T_)*BKB + soff[s],       \
                   Bs + (((T_)&1) * 2 + (h_)) * HALF_BYTES + sdst[s]);      \
  } while (0)

  // swizzled ds_read offsets (16B chunk index = ks*4 + lhi, XOR row&7 = l16&7)
  int axor[2];
#pragma unroll
  for (int ks = 0; ks < 2; ++ks)
    axor[ks] = (((ks * 4 + lhi) ^ (l16 & 7)) << 4);
  const int arow = l16 * 128;
  const int brow = ((wn & 1) * 64 + l16) * 128;

  const v4i vz = {0, 0, 0, 0};
  v4i acc[8][4];
#pragma unroll
  for (int i = 0; i < 8; ++i)
#pragma unroll
    for (int j = 0; j < 4; ++j) acc[i][j] = vz;

  // prologue: tile0 (4 halves) + B0/B1/A0 of tile1; drain to tile0-landed.
  STAGE_A(0, 0); STAGE_A(0, 1); STAGE_B(0, 0); STAGE_B(0, 1);
  STAGE_B(1, 0); STAGE_B(1, 1); STAGE_A(1, 0);
  asm volatile("s_waitcnt vmcnt(6)" ::: "memory");
  __builtin_amdgcn_s_barrier();

#define BAR_IN()                                        \
  do {                                                  \
    __builtin_amdgcn_s_barrier();                       \
    asm volatile("s_waitcnt lgkmcnt(0)" ::: "memory");  \
    __builtin_amdgcn_sched_barrier(0);                  \
    __builtin_amdgcn_s_setprio(1);                      \
  } while (0)
#define BAR_OUT()                                       \
  do {                                                  \
    __builtin_amdgcn_s_setprio(0);                      \
    __builtin_amdgcn_s_barrier();                       \
  } while (0)
#define MFMA_ROW(mi_)                                                        \
  do {                                                                       \
    _Pragma("unroll") for (int nj = 0; nj < 4; ++nj) {                       \
      acc[mi_][nj] = __builtin_amdgcn_mfma_i32_16x16x64_i8(                  \
          a[mi_][0], b[nj][0], acc[mi_][nj], 0, 0, 0);                       \
      acc[mi_][nj] = __builtin_amdgcn_mfma_i32_16x16x64_i8(                  \
          a[mi_][1], b[nj][1], acc[mi_][nj], 0, 0, 0);                       \
    }                                                                        \
  } while (0)

  for (int T = 0; T < NT; ++T) {
    const int buf = T & 1;
    const signed char* Ar = As + (buf * 2 + wm) * HALF_BYTES;
    const signed char* Br = Bs + (buf * 2 + (wn >> 1)) * HALF_BYTES;
    v4i a[8][2], b[4][2];

    // ---- P1
#pragma unroll
    for (int nj = 0; nj < 4; ++nj)
#pragma unroll
      for (int ks = 0; ks < 2; ++ks)
        b[nj][ks] = *(const v4i*)(Br + nj * 2048 + brow + axor[ks]);
#pragma unroll
    for (int mi = 0; mi < 2; ++mi)
#pragma unroll
      for (int ks = 0; ks < 2; ++ks)
        a[mi][ks] = *(const v4i*)(Ar + mi * 2048 + arow + axor[ks]);
    if (T + 1 < NT) STAGE_A(T + 1, 1);
    BAR_IN();
    MFMA_ROW(0); MFMA_ROW(1);
    BAR_OUT();

    // ---- P2
#pragma unroll
    for (int mi = 2; mi < 5; ++mi)
#pragma unroll
      for (int ks = 0; ks < 2; ++ks)
        a[mi][ks] = *(const v4i*)(Ar + mi * 2048 + arow + axor[ks]);
    if (T + 2 < NT) STAGE_B(T + 2, 0);
    BAR_IN();
    MFMA_ROW(2); MFMA_ROW(3);
    BAR_OUT();

    // ---- P3
#pragma unroll
    for (int mi = 5; mi < 8; ++mi)
#pragma unroll
      for (int ks = 0; ks < 2; ++ks)
        a[mi][ks] = *(const v4i*)(Ar + mi * 2048 + arow + axor[ks]);
    if (T + 2 < NT) STAGE_B(T + 2, 1);
    BAR_IN();
    MFMA_ROW(4); MFMA_ROW(5);
    BAR_OUT();

    // ---- P4
    if (T + 2 < NT) STAGE_A(T + 2, 0);
    __builtin_amdgcn_s_barrier();
    __builtin_amdgcn_s_setprio(1);
    MFMA_ROW(6); MFMA_ROW(7);
    __builtin_amdgcn_s_setprio(0);
    if (T < NT - 2)
      asm volatile("s_waitcnt vmcnt(6)" ::: "memory");
    else
      asm volatile("s_waitcnt vmcnt(0)" ::: "memory");
    __builtin_amdgcn_s_barrier();
  }

  // epilogue: C/D layout col = lane&15, row = (lane>>4)*4 + reg
  float sbv[4];
#pragma unroll
  for (int nj = 0; nj < 4; ++nj) sbv[nj] = sB[n0 + wn * 64 + nj * 16 + l16];
#pragma unroll
  for (int mi = 0; mi < 8; ++mi) {
#pragma unroll
    for (int r = 0; r < 4; ++r) {
      const int row = m0 + wm * 128 + mi * 16 + lhi * 4 + r;
      const float sav = sA[row];
      float* crow = C + (size_t)row * N + (n0 + wn * 64 + l16);
#pragma unroll
      for (int nj = 0; nj < 4; ++nj)
        crow[nj * 16] = (float)acc[mi][nj][r] * sav * sbv[nj];
    }
  }
}

extern "C" void kernel_launch(void* const* d_in, const int* in_sizes, int n_in,
                              void* d_out, int out_size, void* d_ws, size_t ws_size,
                              hipStream_t stream) {
  const float* A = (const float*)d_in[0];
  const float* B = (const float*)d_in[1];
  float* C = (float*)d_out;
  const int K = K_DIM;
  const int M = in_sizes[0] / K;  // 8192
  const int N = in_sizes[1] / K;  // 4096

  signed char* qA = (signed char*)d_ws;
  signed char* qB = qA + (size_t)M * K;
  float* sA = (float*)(qB + (size_t)N * K);
  float* sB = sA + M;

  quant_rows_kernel<<<M, TPB_Q, 0, stream>>>(A, qA, sA);
  quant_rows_kernel<<<N, TPB_Q, 0, stream>>>(B, qB, sB);

  dim3 grid(N / BN, M / BM);
  gemm_i8_kernel<<<grid, 512, 0, stream>>>(qA, qB, sA, sB, C, M, N, K);
}

// Round 6
// 195.941 us; speedup vs baseline: 1.2282x; 1.0243x over previous
//
#include <hip/hip_runtime.h>
#include <stdint.h>

typedef int v4i __attribute__((ext_vector_type(4)));

#define K_DIM 4096
#define TPB_Q 256
#define BM 256
#define BN 256
#define BKB 128                     // K-bytes (= i8 elements) per tile
#define NT (K_DIM / BKB)            // 32 K-tiles
#define HALF_BYTES (128 * BKB)      // one half-tile: 128 rows x 128 B = 16 KiB

__device__ __forceinline__ void load_lds16(const void* g, void* l) {
  __builtin_amdgcn_global_load_lds(
      (const __attribute__((address_space(1))) void*)g,
      (__attribute__((address_space(3))) void*)l, 16, 0, 0);
}

// ---------------- per-row symmetric int8 quant (BW-bound, unchanged) --------
__global__ __launch_bounds__(TPB_Q) void quant_rows_kernel(
    const float* __restrict__ x, signed char* __restrict__ q,
    float* __restrict__ scales) {
  const int row = blockIdx.x;
  const float4* xr = (const float4*)(x + (size_t)row * K_DIM);
  float4 v[4];
  float m = 0.0f;
#pragma unroll
  for (int i = 0; i < 4; ++i) {
    v[i] = xr[threadIdx.x + i * TPB_Q];
    m = fmaxf(m, fmaxf(fmaxf(fabsf(v[i].x), fabsf(v[i].y)),
                       fmaxf(fabsf(v[i].z), fabsf(v[i].w))));
  }
#pragma unroll
  for (int off = 32; off > 0; off >>= 1) m = fmaxf(m, __shfl_down(m, off));
  __shared__ float red[TPB_Q / 64];
  if ((threadIdx.x & 63) == 0) red[threadIdx.x >> 6] = m;
  __syncthreads();
  m = fmaxf(fmaxf(red[0], red[1]), fmaxf(red[2], red[3]));
  const float scale = fmaxf(m / 127.0f, 1e-8f);
  if (threadIdx.x == 0) scales[row] = scale;
  uint32_t* qr = (uint32_t*)(q + (size_t)row * K_DIM);
#pragma unroll
  for (int i = 0; i < 4; ++i) {
    const float4 t = v[i];
    const int a0 = (int)fminf(fmaxf(rintf(t.x / scale), -128.0f), 127.0f);
    const int a1 = (int)fminf(fmaxf(rintf(t.y / scale), -128.0f), 127.0f);
    const int a2 = (int)fminf(fmaxf(rintf(t.z / scale), -128.0f), 127.0f);
    const int a3 = (int)fminf(fmaxf(rintf(t.w / scale), -128.0f), 127.0f);
    const uint32_t p = (uint32_t)(a0 & 255) | ((uint32_t)(a1 & 255) << 8) |
                       ((uint32_t)(a2 & 255) << 16) | ((uint32_t)(a3 & 255) << 24);
    qr[threadIdx.x + i * TPB_Q] = p;
  }
}

// ---------------- 256x256 8-phase i8 GEMM --------------------------------
// 8 waves: wm=wave>>2 (2), wn=wave&3 (4). Per-wave C: 128x64 = acc[8][4].
// LDS: per operand 2 dbuf x 2 halves x (128 rows x 128 B), XOR-swizzled
// at 16B-chunk granularity: phys_chunk = logical_chunk ^ (row & 7).
// Schedule per K-tile T (4 phases):
//   P1: read all B frags + a[0..1]; stage A1(T+1); bar; lgkm0; MFMA mi0-1; bar
//   P2: read a[2..4];               stage B0(T+2); bar; lgkm0; MFMA mi2-3; bar
//   P3: read a[5..7];               stage B1(T+2); bar; lgkm0; MFMA mi4-5; bar
//   P4: (no reads)                  stage A0(T+2); bar; MFMA mi6-7; vmcnt(6); bar
// XCD swizzle: grid 32r x 16c; XCD k owns rows[8*(k>>1),+8) x
// cols[8*(k&1),+8); slot order col-fastest => each resident round of ~32
// blocks = 4 rows x 8 cols sharing 4 A-panels + 8 B-panels in its L2.
__global__ __launch_bounds__(512, 2) void gemm_i8_kernel(
    const signed char* __restrict__ qA, const signed char* __restrict__ qB,
    const float* __restrict__ sA, const float* __restrict__ sB,
    float* __restrict__ C, int M, int N, int K) {
  __shared__ __align__(16) signed char As[4 * HALF_BYTES];  // 64 KiB
  __shared__ __align__(16) signed char Bs[4 * HALF_BYTES];  // 64 KiB

  const int tid = threadIdx.x;
  const int wave = tid >> 6, lane = tid & 63;
  const int l16 = lane & 15, lhi = lane >> 4;
  const int wm = wave >> 2, wn = wave & 3;

  // XCD-chunked 2-D swizzle (bijective; 512 blocks, 8 XCDs, o%8 = XCD)
  const int o = blockIdx.x + blockIdx.y * gridDim.x;
  const int xcd = o & 7, slot = o >> 3;
  const int rb = ((xcd >> 1) << 3) + (slot >> 3);  // grid row 0..31
  const int cb = ((xcd & 1) << 3) + (slot & 7);    // grid col 0..15
  const int m0 = rb * BM, n0 = cb * BN;

  const signed char* Abase = qA + (size_t)m0 * K;
  const signed char* Bbase = qB + (size_t)n0 * K;

  // staging: half-tile = 1024 x 16B chunks; thread handles chunks d = s*512+tid.
  // dest is linear (wave-uniform base + lane*16); source is inverse-swizzled.
  int soff[2], sdst[2];
#pragma unroll
  for (int s = 0; s < 2; ++s) {
    const int d = s * 512 + tid;
    const int r = d >> 3;                 // row within half
    const int c = (d & 7) ^ (r & 7);      // logical chunk held at phys (d&7)
    soff[s] = r * K + c * 16;
    sdst[s] = s * 8192 + wave * 1024;
  }

#define STAGE_A(T_, h_)                                                     \
  do {                                                                      \
    _Pragma("unroll") for (int s = 0; s < 2; ++s)                           \
        load_lds16(Abase + (size_t)(h_)*128 * K + (T_)*BKB + soff[s],       \
                   As + (((T_)&1) * 2 + (h_)) * HALF_BYTES + sdst[s]);      \
  } while (0)
#define STAGE_B(T_, h_)                                                     \
  do {                                                                      \
    _Pragma("unroll") for (int s = 0; s < 2; ++s)                           \
        load_lds16(Bbase + (size_t)(h_)*128 * K + (T_)*BKB + soff[s],       \
                   Bs + (((T_)&1) * 2 + (h_)) * HALF_BYTES + sdst[s]);      \
  } while (0)

  // swizzled ds_read offsets (16B chunk index = ks*4 + lhi, XOR row&7 = l16&7)
  int axor[2];
#pragma unroll
  for (int ks = 0; ks < 2; ++ks)
    axor[ks] = (((ks * 4 + lhi) ^ (l16 & 7)) << 4);
  const int arow = l16 * 128;
  const int brow = ((wn & 1) * 64 + l16) * 128;

  const v4i vz = {0, 0, 0, 0};
  v4i acc[8][4];
#pragma unroll
  for (int i = 0; i < 8; ++i)
#pragma unroll
    for (int j = 0; j < 4; ++j) acc[i][j] = vz;

  // prologue: tile0 (4 halves) + B0/B1/A0 of tile1; drain to tile0-landed.
  STAGE_A(0, 0); STAGE_A(0, 1); STAGE_B(0, 0); STAGE_B(0, 1);
  STAGE_B(1, 0); STAGE_B(1, 1); STAGE_A(1, 0);
  asm volatile("s_waitcnt vmcnt(6)" ::: "memory");
  __builtin_amdgcn_s_barrier();

#define BAR_IN()                                        \
  do {                                                  \
    __builtin_amdgcn_s_barrier();                       \
    asm volatile("s_waitcnt lgkmcnt(0)" ::: "memory");  \
    __builtin_amdgcn_sched_barrier(0);                  \
    __builtin_amdgcn_s_setprio(1);                      \
  } while (0)
#define BAR_OUT()                                       \
  do {                                                  \
    __builtin_amdgcn_s_setprio(0);                      \
    __builtin_amdgcn_s_barrier();                       \
  } while (0)
#define MFMA_ROW(mi_)                                                        \
  do {                                                                       \
    _Pragma("unroll") for (int nj = 0; nj < 4; ++nj) {                       \
      acc[mi_][nj] = __builtin_amdgcn_mfma_i32_16x16x64_i8(                  \
          a[mi_][0], b[nj][0], acc[mi_][nj], 0, 0, 0);                       \
      acc[mi_][nj] = __builtin_amdgcn_mfma_i32_16x16x64_i8(                  \
          a[mi_][1], b[nj][1], acc[mi_][nj], 0, 0, 0);                       \
    }                                                                        \
  } while (0)

  for (int T = 0; T < NT; ++T) {
    const int buf = T & 1;
    const signed char* Ar = As + (buf * 2 + wm) * HALF_BYTES;
    const signed char* Br = Bs + (buf * 2 + (wn >> 1)) * HALF_BYTES;
    v4i a[8][2], b[4][2];

    // ---- P1
#pragma unroll
    for (int nj = 0; nj < 4; ++nj)
#pragma unroll
      for (int ks = 0; ks < 2; ++ks)
        b[nj][ks] = *(const v4i*)(Br + nj * 2048 + brow + axor[ks]);
#pragma unroll
    for (int mi = 0; mi < 2; ++mi)
#pragma unroll
      for (int ks = 0; ks < 2; ++ks)
        a[mi][ks] = *(const v4i*)(Ar + mi * 2048 + arow + axor[ks]);
    if (T + 1 < NT) STAGE_A(T + 1, 1);
    BAR_IN();
    MFMA_ROW(0); MFMA_ROW(1);
    BAR_OUT();

    // ---- P2
#pragma unroll
    for (int mi = 2; mi < 5; ++mi)
#pragma unroll
      for (int ks = 0; ks < 2; ++ks)
        a[mi][ks] = *(const v4i*)(Ar + mi * 2048 + arow + axor[ks]);
    if (T + 2 < NT) STAGE_B(T + 2, 0);
    BAR_IN();
    MFMA_ROW(2); MFMA_ROW(3);
    BAR_OUT();

    // ---- P3
#pragma unroll
    for (int mi = 5; mi < 8; ++mi)
#pragma unroll
      for (int ks = 0; ks < 2; ++ks)
        a[mi][ks] = *(const v4i*)(Ar + mi * 2048 + arow + axor[ks]);
    if (T + 2 < NT) STAGE_B(T + 2, 1);
    BAR_IN();
    MFMA_ROW(4); MFMA_ROW(5);
    BAR_OUT();

    // ---- P4
    if (T + 2 < NT) STAGE_A(T + 2, 0);
    __builtin_amdgcn_s_barrier();
    __builtin_amdgcn_s_setprio(1);
    MFMA_ROW(6); MFMA_ROW(7);
    __builtin_amdgcn_s_setprio(0);
    if (T < NT - 2)
      asm volatile("s_waitcnt vmcnt(6)" ::: "memory");
    else
      asm volatile("s_waitcnt vmcnt(0)" ::: "memory");
    __builtin_amdgcn_s_barrier();
  }

  // epilogue: C/D layout col = lane&15, row = (lane>>4)*4 + reg
  float sbv[4];
#pragma unroll
  for (int nj = 0; nj < 4; ++nj) sbv[nj] = sB[n0 + wn * 64 + nj * 16 + l16];
#pragma unroll
  for (int mi = 0; mi < 8; ++mi) {
#pragma unroll
    for (int r = 0; r < 4; ++r) {
      const int row = m0 + wm * 128 + mi * 16 + lhi * 4 + r;
      const float sav = sA[row];
      float* crow = C + (size_t)row * N + (n0 + wn * 64 + l16);
#pragma unroll
      for (int nj = 0; nj < 4; ++nj)
        crow[nj * 16] = (float)acc[mi][nj][r] * sav * sbv[nj];
    }
  }
}

extern "C" void kernel_launch(void* const* d_in, const int* in_sizes, int n_in,
                              void* d_out, int out_size, void* d_ws, size_t ws_size,
                              hipStream_t stream) {
  const float* A = (const float*)d_in[0];
  const float* B = (const float*)d_in[1];
  float* C = (float*)d_out;
  const int K = K_DIM;
  const int M = in_sizes[0] / K;  // 8192
  const int N = in_sizes[1] / K;  // 4096

  signed char* qA = (signed char*)d_ws;
  signed char* qB = qA + (size_t)M * K;
  float* sA = (float*)(qB + (size_t)N * K);
  float* sB = sA + M;

  quant_rows_kernel<<<M, TPB_Q, 0, stream>>>(A, qA, sA);
  quant_rows_kernel<<<N, TPB_Q, 0, stream>>>(B, qB, sB);

  dim3 grid(N / BN, M / BM);
  gemm_i8_kernel<<<grid, 512, 0, stream>>>(qA, qB, sA, sB, C, M, N, K);
}

// Round 7
// 194.222 us; speedup vs baseline: 1.2390x; 1.0088x over previous
//
#include <hip/hip_runtime.h>
#include <stdint.h>

typedef int v4i __attribute__((ext_vector_type(4)));

#define K_DIM 4096
#define TPB_Q 256
#define BM 256
#define BN 256
#define BKB 128                     // K-bytes (= i8 elements) per tile
#define NT (K_DIM / BKB)            // 32 K-tiles
#define HALF_BYTES (128 * BKB)      // one half-tile: 128 rows x 128 B = 16 KiB

__device__ __forceinline__ void load_lds16(const void* g, void* l) {
  __builtin_amdgcn_global_load_lds(
      (const __attribute__((address_space(1))) void*)g,
      (__attribute__((address_space(3))) void*)l, 16, 0, 0);
}

// ---------------- per-row symmetric int8 quant (BW-bound, unchanged) --------
__global__ __launch_bounds__(TPB_Q) void quant_rows_kernel(
    const float* __restrict__ x, signed char* __restrict__ q,
    float* __restrict__ scales) {
  const int row = blockIdx.x;
  const float4* xr = (const float4*)(x + (size_t)row * K_DIM);
  float4 v[4];
  float m = 0.0f;
#pragma unroll
  for (int i = 0; i < 4; ++i) {
    v[i] = xr[threadIdx.x + i * TPB_Q];
    m = fmaxf(m, fmaxf(fmaxf(fabsf(v[i].x), fabsf(v[i].y)),
                       fmaxf(fabsf(v[i].z), fabsf(v[i].w))));
  }
#pragma unroll
  for (int off = 32; off > 0; off >>= 1) m = fmaxf(m, __shfl_down(m, off));
  __shared__ float red[TPB_Q / 64];
  if ((threadIdx.x & 63) == 0) red[threadIdx.x >> 6] = m;
  __syncthreads();
  m = fmaxf(fmaxf(red[0], red[1]), fmaxf(red[2], red[3]));
  const float scale = fmaxf(m / 127.0f, 1e-8f);
  if (threadIdx.x == 0) scales[row] = scale;
  uint32_t* qr = (uint32_t*)(q + (size_t)row * K_DIM);
#pragma unroll
  for (int i = 0; i < 4; ++i) {
    const float4 t = v[i];
    const int a0 = (int)fminf(fmaxf(rintf(t.x / scale), -128.0f), 127.0f);
    const int a1 = (int)fminf(fmaxf(rintf(t.y / scale), -128.0f), 127.0f);
    const int a2 = (int)fminf(fmaxf(rintf(t.z / scale), -128.0f), 127.0f);
    const int a3 = (int)fminf(fmaxf(rintf(t.w / scale), -128.0f), 127.0f);
    const uint32_t p = (uint32_t)(a0 & 255) | ((uint32_t)(a1 & 255) << 8) |
                       ((uint32_t)(a2 & 255) << 16) | ((uint32_t)(a3 & 255) << 24);
    qr[threadIdx.x + i * TPB_Q] = p;
  }
}

// ---------------- 256x256 i8 GEMM, counted-lgkm pipeline -------------------
// 8 waves: wm=wave>>2 (2), wn=wave&3 (4). Per-wave C: 128x64 = acc[8][4].
// LDS: per operand 2 dbuf x 2 halves x (128 rows x 128 B), XOR-swizzled
// at 16B-chunk granularity: phys_chunk = logical_chunk ^ (row & 7).
// Per K-tile T: issue ALL 24 ds_reads (b x8, a01 x4 | a234 x6 | a567 x6,
// order pinned by sched_barrier(0)); then 3 MFMA clusters gated by
// lgkmcnt(12)/(6)/(0) so the LDS pipe streams under the matrix pipe.
// Fences: bar1 after lgkm(12) (all waves' B reads drained, DS in-order) ->
// STAGE_B(T+2) safe; bar2 after lgkm(0) -> STAGE_A(T+2,0) safe; vmcnt(6)
// at tile end leaves only T+2's 3 half-tiles outstanding (8 loads/tile).
// XCD swizzle: grid 32r x 16c; XCD k owns rows[8*(k>>1),+8) x cols[8*(k&1),+8).
__global__ __launch_bounds__(512, 2) void gemm_i8_kernel(
    const signed char* __restrict__ qA, const signed char* __restrict__ qB,
    const float* __restrict__ sA, const float* __restrict__ sB,
    float* __restrict__ C, int M, int N, int K) {
  __shared__ __align__(16) signed char As[4 * HALF_BYTES];  // 64 KiB
  __shared__ __align__(16) signed char Bs[4 * HALF_BYTES];  // 64 KiB

  const int tid = threadIdx.x;
  const int wave = tid >> 6, lane = tid & 63;
  const int l16 = lane & 15, lhi = lane >> 4;
  const int wm = wave >> 2, wn = wave & 3;

  // XCD-chunked 2-D swizzle (bijective; 512 blocks, 8 XCDs, o%8 = XCD)
  const int o = blockIdx.x + blockIdx.y * gridDim.x;
  const int xcd = o & 7, slot = o >> 3;
  const int rb = ((xcd >> 1) << 3) + (slot >> 3);  // grid row 0..31
  const int cb = ((xcd & 1) << 3) + (slot & 7);    // grid col 0..15
  const int m0 = rb * BM, n0 = cb * BN;

  const signed char* Abase = qA + (size_t)m0 * K;
  const signed char* Bbase = qB + (size_t)n0 * K;

  // staging: half-tile = 1024 x 16B chunks; thread handles chunks d = s*512+tid.
  // dest is linear (wave-uniform base + lane*16); source is inverse-swizzled.
  int soff[2], sdst[2];
#pragma unroll
  for (int s = 0; s < 2; ++s) {
    const int d = s * 512 + tid;
    const int r = d >> 3;                 // row within half
    const int c = (d & 7) ^ (r & 7);      // logical chunk held at phys (d&7)
    soff[s] = r * K + c * 16;
    sdst[s] = s * 8192 + wave * 1024;
  }

#define STAGE_A(T_, h_)                                                     \
  do {                                                                      \
    _Pragma("unroll") for (int s = 0; s < 2; ++s)                           \
        load_lds16(Abase + (size_t)(h_)*128 * K + (T_)*BKB + soff[s],       \
                   As + (((T_)&1) * 2 + (h_)) * HALF_BYTES + sdst[s]);      \
  } while (0)
#define STAGE_B(T_, h_)                                                     \
  do {                                                                      \
    _Pragma("unroll") for (int s = 0; s < 2; ++s)                           \
        load_lds16(Bbase + (size_t)(h_)*128 * K + (T_)*BKB + soff[s],       \
                   Bs + (((T_)&1) * 2 + (h_)) * HALF_BYTES + sdst[s]);      \
  } while (0)

  // swizzled ds_read offsets (16B chunk index = ks*4 + lhi, XOR row&7 = l16&7)
  int axor[2];
#pragma unroll
  for (int ks = 0; ks < 2; ++ks)
    axor[ks] = (((ks * 4 + lhi) ^ (l16 & 7)) << 4);
  const int arow = l16 * 128;
  const int brow = ((wn & 1) * 64 + l16) * 128;

  const v4i vz = {0, 0, 0, 0};
  v4i acc[8][4];
#pragma unroll
  for (int i = 0; i < 8; ++i)
#pragma unroll
    for (int j = 0; j < 4; ++j) acc[i][j] = vz;

  // prologue: tile0 (4 halves) + B0/B1/A0 of tile1; drain to tile0-landed.
  STAGE_A(0, 0); STAGE_A(0, 1); STAGE_B(0, 0); STAGE_B(0, 1);
  STAGE_B(1, 0); STAGE_B(1, 1); STAGE_A(1, 0);
  asm volatile("s_waitcnt vmcnt(6)" ::: "memory");
  __builtin_amdgcn_s_barrier();

// ks-outer: 4 independent nj chains between dependent (ks0->ks1) pairs
#define MFMA_ROW(mi_)                                                        \
  do {                                                                       \
    _Pragma("unroll") for (int ks = 0; ks < 2; ++ks)                         \
        _Pragma("unroll") for (int nj = 0; nj < 4; ++nj)                     \
            acc[mi_][nj] = __builtin_amdgcn_mfma_i32_16x16x64_i8(            \
                a[mi_][ks], b[nj][ks], acc[mi_][nj], 0, 0, 0);               \
  } while (0)

  for (int T = 0; T < NT; ++T) {
    const int buf = T & 1;
    const signed char* Ar = As + (buf * 2 + wm) * HALF_BYTES;
    const signed char* Br = Bs + (buf * 2 + (wn >> 1)) * HALF_BYTES;
    v4i a[8][2], b[4][2];

    // ---- issue all fragment reads, order pinned: b(8), a01(4) | a234 | a567
#pragma unroll
    for (int nj = 0; nj < 4; ++nj)
#pragma unroll
      for (int ks = 0; ks < 2; ++ks)
        b[nj][ks] = *(const v4i*)(Br + nj * 2048 + brow + axor[ks]);
#pragma unroll
    for (int mi = 0; mi < 2; ++mi)
#pragma unroll
      for (int ks = 0; ks < 2; ++ks)
        a[mi][ks] = *(const v4i*)(Ar + mi * 2048 + arow + axor[ks]);
    __builtin_amdgcn_sched_barrier(0);
#pragma unroll
    for (int mi = 2; mi < 5; ++mi)
#pragma unroll
      for (int ks = 0; ks < 2; ++ks)
        a[mi][ks] = *(const v4i*)(Ar + mi * 2048 + arow + axor[ks]);
    __builtin_amdgcn_sched_barrier(0);
#pragma unroll
    for (int mi = 5; mi < 8; ++mi)
#pragma unroll
      for (int ks = 0; ks < 2; ++ks)
        a[mi][ks] = *(const v4i*)(Ar + mi * 2048 + arow + axor[ks]);
    __builtin_amdgcn_sched_barrier(0);

    if (T + 1 < NT) STAGE_A(T + 1, 1);

    asm volatile("s_waitcnt lgkmcnt(12)" ::: "memory");  // b + a01 drained
    __builtin_amdgcn_sched_barrier(0);
    __builtin_amdgcn_s_barrier();  // fence: all waves' B reads done
    if (T + 2 < NT) { STAGE_B(T + 2, 0); STAGE_B(T + 2, 1); }

    __builtin_amdgcn_s_setprio(1);
    MFMA_ROW(0); MFMA_ROW(1);
    __builtin_amdgcn_s_setprio(0);

    asm volatile("s_waitcnt lgkmcnt(6)" ::: "memory");   // a234 drained
    __builtin_amdgcn_sched_barrier(0);
    __builtin_amdgcn_s_setprio(1);
    MFMA_ROW(2); MFMA_ROW(3); MFMA_ROW(4);
    __builtin_amdgcn_s_setprio(0);

    asm volatile("s_waitcnt lgkmcnt(0)" ::: "memory");   // a567 drained
    __builtin_amdgcn_sched_barrier(0);
    __builtin_amdgcn_s_setprio(1);
    MFMA_ROW(5); MFMA_ROW(6); MFMA_ROW(7);
    __builtin_amdgcn_s_setprio(0);

    __builtin_amdgcn_s_barrier();  // fence: all waves' A reads done
    if (T + 2 < NT) STAGE_A(T + 2, 0);
    if (T < NT - 2)
      asm volatile("s_waitcnt vmcnt(6)" ::: "memory");
    else
      asm volatile("s_waitcnt vmcnt(0)" ::: "memory");
    __builtin_amdgcn_s_barrier();  // tile boundary: T+1 fully landed
  }

  // epilogue: C/D layout col = lane&15, row = (lane>>4)*4 + reg
  float sbv[4];
#pragma unroll
  for (int nj = 0; nj < 4; ++nj) sbv[nj] = sB[n0 + wn * 64 + nj * 16 + l16];
#pragma unroll
  for (int mi = 0; mi < 8; ++mi) {
#pragma unroll
    for (int r = 0; r < 4; ++r) {
      const int row = m0 + wm * 128 + mi * 16 + lhi * 4 + r;
      const float sav = sA[row];
      float* crow = C + (size_t)row * N + (n0 + wn * 64 + l16);
#pragma unroll
      for (int nj = 0; nj < 4; ++nj)
        crow[nj * 16] = (float)acc[mi][nj][r] * sav * sbv[nj];
    }
  }
}

extern "C" void kernel_launch(void* const* d_in, const int* in_sizes, int n_in,
                              void* d_out, int out_size, void* d_ws, size_t ws_size,
                              hipStream_t stream) {
  const float* A = (const float*)d_in[0];
  const float* B = (const float*)d_in[1];
  float* C = (float*)d_out;
  const int K = K_DIM;
  const int M = in_sizes[0] / K;  // 8192
  const int N = in_sizes[1] / K;  // 4096

  signed char* qA = (signed char*)d_ws;
  signed char* qB = qA + (size_t)M * K;
  float* sA = (float*)(qB + (size_t)N * K);
  float* sB = sA + M;

  quant_rows_kernel<<<M, TPB_Q, 0, stream>>>(A, qA, sA);
  quant_rows_kernel<<<N, TPB_Q, 0, stream>>>(B, qB, sB);

  dim3 grid(N / BN, M / BM);
  gemm_i8_kernel<<<grid, 512, 0, stream>>>(qA, qB, sA, sB, C, M, N, K);
}

// Round 8
// 176.780 us; speedup vs baseline: 1.3613x; 1.0987x over previous
//
#include <hip/hip_runtime.h>
#include <stdint.h>

typedef int v4i __attribute__((ext_vector_type(4)));

#define K_DIM 4096
#define TPB_Q 256
#define BM 256
#define BN 256
#define BKB 128                     // K-bytes per tile
#define NT (K_DIM / BKB)            // 32 K-tiles
#define TILE_BYTES (256 * BKB)      // 32 KiB per operand tile

__device__ __forceinline__ void load_lds16(const void* g, void* l) {
  __builtin_amdgcn_global_load_lds(
      (const __attribute__((address_space(1))) void*)g,
      (__attribute__((address_space(3))) void*)l, 16, 0, 0);
}

// ---------------- per-row symmetric int8 quant (BW-bound, unchanged) --------
__global__ __launch_bounds__(TPB_Q) void quant_rows_kernel(
    const float* __restrict__ x, signed char* __restrict__ q,
    float* __restrict__ scales) {
  const int row = blockIdx.x;
  const float4* xr = (const float4*)(x + (size_t)row * K_DIM);
  float4 v[4];
  float m = 0.0f;
#pragma unroll
  for (int i = 0; i < 4; ++i) {
    v[i] = xr[threadIdx.x + i * TPB_Q];
    m = fmaxf(m, fmaxf(fmaxf(fabsf(v[i].x), fabsf(v[i].y)),
                       fmaxf(fabsf(v[i].z), fabsf(v[i].w))));
  }
#pragma unroll
  for (int off = 32; off > 0; off >>= 1) m = fmaxf(m, __shfl_down(m, off));
  __shared__ float red[TPB_Q / 64];
  if ((threadIdx.x & 63) == 0) red[threadIdx.x >> 6] = m;
  __syncthreads();
  m = fmaxf(fmaxf(red[0], red[1]), fmaxf(red[2], red[3]));
  const float scale = fmaxf(m / 127.0f, 1e-8f);
  if (threadIdx.x == 0) scales[row] = scale;
  uint32_t* qr = (uint32_t*)(q + (size_t)row * K_DIM);
#pragma unroll
  for (int i = 0; i < 4; ++i) {
    const float4 t = v[i];
    const int a0 = (int)fminf(fmaxf(rintf(t.x / scale), -128.0f), 127.0f);
    const int a1 = (int)fminf(fmaxf(rintf(t.y / scale), -128.0f), 127.0f);
    const int a2 = (int)fminf(fmaxf(rintf(t.z / scale), -128.0f), 127.0f);
    const int a3 = (int)fminf(fmaxf(rintf(t.w / scale), -128.0f), 127.0f);
    const uint32_t p = (uint32_t)(a0 & 255) | ((uint32_t)(a1 & 255) << 8) |
                       ((uint32_t)(a2 & 255) << 16) | ((uint32_t)(a3 & 255) << 24);
    qr[threadIdx.x + i * TPB_Q] = p;
  }
}

// ---------------- 256x256 i8 GEMM, 1-barrier-per-tile free-run -------------
// 8 waves: wm=wave>>2 (2), wn=wave&3 (4). Per-wave C: 128x64 = acc[8][4].
// LDS: full-tile double buffer per operand (2 x 32 KiB each, 128 KiB total),
// XOR-swizzled at 16B-chunk granularity: phys_chunk = logical ^ (row&7).
// Per K-tile T (NO intra-tile barriers):
//   issue 24 ds_reads (pinned: b x8 + a01 x4 | a23 | a45 | a67)
//   issue full stage of T+1 into buf^1 (8 x global_load_lds)
//   MFMA pair-clusters gated by lgkmcnt(12)/(8)/(4)/(0)  <- waves free-run,
//     fast wave enters MFMA while LDS pipe serves slow waves (m114 overlap)
//   vmcnt(0)  (own stage landed; had full MFMA span to arrive)
//   s_barrier (cross-wave: everyone's stage landed; reads of buf done
//              before next tile's stage overwrites buf^1 cycle)
// XCD swizzle: grid 32r x 16c; XCD k owns rows[8*(k>>1),+8) x cols[8*(k&1),+8).
__global__ __launch_bounds__(512, 2) void gemm_i8_kernel(
    const signed char* __restrict__ qA, const signed char* __restrict__ qB,
    const float* __restrict__ sA, const float* __restrict__ sB,
    float* __restrict__ C, int M, int N, int K) {
  __shared__ __align__(16) signed char As[2 * TILE_BYTES];  // 64 KiB
  __shared__ __align__(16) signed char Bs[2 * TILE_BYTES];  // 64 KiB

  const int tid = threadIdx.x;
  const int wave = tid >> 6, lane = tid & 63;
  const int l16 = lane & 15, lhi = lane >> 4;
  const int wm = wave >> 2, wn = wave & 3;

  // XCD-chunked 2-D swizzle (bijective; 512 blocks, 8 XCDs, o%8 = XCD)
  const int o = blockIdx.x + blockIdx.y * gridDim.x;
  const int xcd = o & 7, slot = o >> 3;
  const int rb = ((xcd >> 1) << 3) + (slot >> 3);  // grid row 0..31
  const int cb = ((xcd & 1) << 3) + (slot & 7);    // grid col 0..15
  const int m0 = rb * BM, n0 = cb * BN;

  const signed char* Abase = qA + (size_t)m0 * K;
  const signed char* Bbase = qB + (size_t)n0 * K;

  // staging: tile = 2048 x 16B chunks; thread handles d = s*512+tid, s=0..3.
  // dest linear (wave-uniform base + lane*16); source inverse-swizzled.
  int soff[4], sdst[4];
#pragma unroll
  for (int s = 0; s < 4; ++s) {
    const int d = s * 512 + tid;
    const int r = d >> 3;                 // row 0..255
    const int c = (d & 7) ^ (r & 7);      // logical chunk at phys (d&7)
    soff[s] = r * K + c * 16;
    sdst[s] = s * 8192 + wave * 1024;
  }

#define STAGE_A(T_)                                                         \
  do {                                                                      \
    _Pragma("unroll") for (int s = 0; s < 4; ++s)                           \
        load_lds16(Abase + (size_t)(T_)*BKB + soff[s],                      \
                   As + ((T_)&1) * TILE_BYTES + sdst[s]);                   \
  } while (0)
#define STAGE_B(T_)                                                         \
  do {                                                                      \
    _Pragma("unroll") for (int s = 0; s < 4; ++s)                           \
        load_lds16(Bbase + (size_t)(T_)*BKB + soff[s],                      \
                   Bs + ((T_)&1) * TILE_BYTES + sdst[s]);                   \
  } while (0)

  // swizzled ds_read offsets: chunk = ks*4+lhi, row&7 = l16&7 (mi*16,wm*128,
  // wn*64 all multiples of 8 -> row&7 reduces to l16&7)
  int axor[2];
#pragma unroll
  for (int ks = 0; ks < 2; ++ks)
    axor[ks] = (((ks * 4 + lhi) ^ (l16 & 7)) << 4);
  const int aoff = wm * 16384 + l16 * 128;            // + mi*2048
  const int boff = wn * 8192 + l16 * 128;             // + nj*2048

  const v4i vz = {0, 0, 0, 0};
  v4i acc[8][4];
#pragma unroll
  for (int i = 0; i < 8; ++i)
#pragma unroll
    for (int j = 0; j < 4; ++j) acc[i][j] = vz;

  // prologue: stage tile 0, drain, sync.
  STAGE_A(0); STAGE_B(0);
  asm volatile("s_waitcnt vmcnt(0)" ::: "memory");
  __builtin_amdgcn_s_barrier();

// two mi-rows interleaved per ks: dependent acc reuse is 8 instrs apart
#define MFMA_PAIR(p0_, p1_)                                                  \
  do {                                                                       \
    _Pragma("unroll") for (int ks = 0; ks < 2; ++ks) {                       \
      _Pragma("unroll") for (int nj = 0; nj < 4; ++nj)                       \
          acc[p0_][nj] = __builtin_amdgcn_mfma_i32_16x16x64_i8(              \
              a[p0_][ks], b[nj][ks], acc[p0_][nj], 0, 0, 0);                 \
      _Pragma("unroll") for (int nj = 0; nj < 4; ++nj)                       \
          acc[p1_][nj] = __builtin_amdgcn_mfma_i32_16x16x64_i8(              \
              a[p1_][ks], b[nj][ks], acc[p1_][nj], 0, 0, 0);                 \
    }                                                                        \
  } while (0)

#define LGKM_GATE(n_)                                       \
  do {                                                      \
    asm volatile("s_waitcnt lgkmcnt(" #n_ ")" ::: "memory");\
    __builtin_amdgcn_sched_barrier(0);                      \
  } while (0)

  for (int T = 0; T < NT; ++T) {
    const signed char* Ar = As + (T & 1) * TILE_BYTES;
    const signed char* Br = Bs + (T & 1) * TILE_BYTES;
    v4i a[8][2], b[4][2];

    // ---- pinned read issue: b(8) + a01(4) | a23(4) | a45(4) | a67(4)
#pragma unroll
    for (int nj = 0; nj < 4; ++nj)
#pragma unroll
      for (int ks = 0; ks < 2; ++ks)
        b[nj][ks] = *(const v4i*)(Br + boff + nj * 2048 + axor[ks]);
#pragma unroll
    for (int mi = 0; mi < 2; ++mi)
#pragma unroll
      for (int ks = 0; ks < 2; ++ks)
        a[mi][ks] = *(const v4i*)(Ar + aoff + mi * 2048 + axor[ks]);
    __builtin_amdgcn_sched_barrier(0);
#pragma unroll
    for (int mi = 2; mi < 4; ++mi)
#pragma unroll
      for (int ks = 0; ks < 2; ++ks)
        a[mi][ks] = *(const v4i*)(Ar + aoff + mi * 2048 + axor[ks]);
    __builtin_amdgcn_sched_barrier(0);
#pragma unroll
    for (int mi = 4; mi < 6; ++mi)
#pragma unroll
      for (int ks = 0; ks < 2; ++ks)
        a[mi][ks] = *(const v4i*)(Ar + aoff + mi * 2048 + axor[ks]);
    __builtin_amdgcn_sched_barrier(0);
#pragma unroll
    for (int mi = 6; mi < 8; ++mi)
#pragma unroll
      for (int ks = 0; ks < 2; ++ks)
        a[mi][ks] = *(const v4i*)(Ar + aoff + mi * 2048 + axor[ks]);
    __builtin_amdgcn_sched_barrier(0);

    // ---- stage next tile into buf^1 (no WAR: reads are from buf)
    if (T + 1 < NT) { STAGE_A(T + 1); STAGE_B(T + 1); }

    // ---- MFMA clusters, counted lgkm gates, NO barriers between
    LGKM_GATE(12);
    __builtin_amdgcn_s_setprio(1);
    MFMA_PAIR(0, 1);
    __builtin_amdgcn_s_setprio(0);
    LGKM_GATE(8);
    __builtin_amdgcn_s_setprio(1);
    MFMA_PAIR(2, 3);
    __builtin_amdgcn_s_setprio(0);
    LGKM_GATE(4);
    __builtin_amdgcn_s_setprio(1);
    MFMA_PAIR(4, 5);
    __builtin_amdgcn_s_setprio(0);
    LGKM_GATE(0);
    __builtin_amdgcn_s_setprio(1);
    MFMA_PAIR(6, 7);
    __builtin_amdgcn_s_setprio(0);

    // ---- tile boundary: own stage landed (free: MFMA span covered it),
    // then cross-wave fence.
    asm volatile("s_waitcnt vmcnt(0)" ::: "memory");
    __builtin_amdgcn_s_barrier();
  }

  // epilogue: C/D layout col = lane&15, row = (lane>>4)*4 + reg
  float sbv[4];
#pragma unroll
  for (int nj = 0; nj < 4; ++nj) sbv[nj] = sB[n0 + wn * 64 + nj * 16 + l16];
#pragma unroll
  for (int mi = 0; mi < 8; ++mi) {
#pragma unroll
    for (int r = 0; r < 4; ++r) {
      const int row = m0 + wm * 128 + mi * 16 + lhi * 4 + r;
      const float sav = sA[row];
      float* crow = C + (size_t)row * N + (n0 + wn * 64 + l16);
#pragma unroll
      for (int nj = 0; nj < 4; ++nj)
        crow[nj * 16] = (float)acc[mi][nj][r] * sav * sbv[nj];
    }
  }
}

extern "C" void kernel_launch(void* const* d_in, const int* in_sizes, int n_in,
                              void* d_out, int out_size, void* d_ws, size_t ws_size,
                              hipStream_t stream) {
  const float* A = (const float*)d_in[0];
  const float* B = (const float*)d_in[1];
  float* C = (float*)d_out;
  const int K = K_DIM;
  const int M = in_sizes[0] / K;  // 8192
  const int N = in_sizes[1] / K;  // 4096

  signed char* qA = (signed char*)d_ws;
  signed char* qB = qA + (size_t)M * K;
  float* sA = (float*)(qB + (size_t)N * K);
  float* sB = sA + M;

  quant_rows_kernel<<<M, TPB_Q, 0, stream>>>(A, qA, sA);
  quant_rows_kernel<<<N, TPB_Q, 0, stream>>>(B, qB, sB);

  dim3 grid(N / BN, M / BM);
  gemm_i8_kernel<<<grid, 512, 0, stream>>>(qA, qB, sA, sB, C, M, N, K);
}